// Round 1
// baseline (373.658 us; speedup 1.0000x reference)
//
#include <hip/hip_runtime.h>

#define E     1024
#define HEADS 16
#define HD    64
#define FFD   4096
#define TT    2048
#define MMDIM 4096   // B*T

typedef __bf16 bf16x8 __attribute__((ext_vector_type(8)));
typedef float f32x4 __attribute__((ext_vector_type(4)));
typedef unsigned short u16;
typedef u16 ushort8 __attribute__((ext_vector_type(8)));
typedef u16 us4 __attribute__((ext_vector_type(4)));

__device__ __forceinline__ u16 f2bf(float f) {
  unsigned u = __float_as_uint(f);
  u = (u + 0x7fffu + ((u >> 16) & 1u)) >> 16;
  return (u16)u;
}

__device__ __forceinline__ void gload_lds16(const void* g, void* l) {
  __builtin_amdgcn_global_load_lds((__attribute__((address_space(1))) void*)g,
                                   (__attribute__((address_space(3))) void*)l,
                                   16, 0, 0);
}

// ---------------- LayerNorm: fp32 in -> bf16 out ----------------
__global__ void __launch_bounds__(256) ln_kernel(const float* __restrict__ x,
                                                 const float* __restrict__ g,
                                                 const float* __restrict__ b,
                                                 u16* __restrict__ out) {
  int row = blockIdx.x;
  int t = threadIdx.x;
  const float4 v = reinterpret_cast<const float4*>(x + (size_t)row * E)[t];
  float s = v.x + v.y + v.z + v.w;
  float s2 = v.x * v.x + v.y * v.y + v.z * v.z + v.w * v.w;
#pragma unroll
  for (int m = 1; m < 64; m <<= 1) {
    s += __shfl_xor(s, m);
    s2 += __shfl_xor(s2, m);
  }
  __shared__ float red[8];
  int wave = t >> 6, lane = t & 63;
  if (lane == 0) { red[wave] = s; red[wave + 4] = s2; }
  __syncthreads();
  s = red[0] + red[1] + red[2] + red[3];
  s2 = red[4] + red[5] + red[6] + red[7];
  float mean = s * (1.f / E);
  float var = s2 * (1.f / E) - mean * mean;
  float inv = rsqrtf(var + 1e-5f);
  const float4 gv = reinterpret_cast<const float4*>(g)[t];
  const float4 bv = reinterpret_cast<const float4*>(b)[t];
  us4 pk;
  pk.x = f2bf((v.x - mean) * inv * gv.x + bv.x);
  pk.y = f2bf((v.y - mean) * inv * gv.y + bv.y);
  pk.z = f2bf((v.z - mean) * inv * gv.z + bv.z);
  pk.w = f2bf((v.w - mean) * inv * gv.w + bv.w);
  *(us4*)(out + (size_t)row * E + t * 4) = pk;
}

// ------------- Transpose+convert: W[K,N] fp32 -> Wt[N,K] bf16 -------------
__global__ void __launch_bounds__(256) transpose_bf16(const float* __restrict__ in,
                                                      u16* __restrict__ out,
                                                      int K, int N) {
  __shared__ float tile[32][33];
  int k0 = blockIdx.y * 32, n0 = blockIdx.x * 32;
  int tx = threadIdx.x, ty = threadIdx.y;  // block (32,8)
#pragma unroll
  for (int i = ty; i < 32; i += 8)
    tile[i][tx] = in[(size_t)(k0 + i) * N + n0 + tx];
  __syncthreads();
#pragma unroll
  for (int i = ty; i < 32; i += 8)
    out[(size_t)(n0 + i) * K + k0 + tx] = f2bf(tile[tx][i]);
}

// ------------- GEMM C[M,N] = A[M,K](bf16) @ Bt[N,K](bf16)^T -------------
// m97 structure: 128x128 tile, BK=32, 4 waves (2x2), 4x4 16x16 frags/wave.
// MODE 0: +qkv_b, scatter Q(*0.125)/K -> [BH,T,D], V -> [BH,D,T]
// MODE 1: +out_b +resid -> fp32 of
// MODE 2: +ff_b1, exact GELU -> bf16 ob0
// MODE 3: +ff_b2 +resid -> fp32 of
template <int MODE>
__global__ void __launch_bounds__(256) gemm_bt(const u16* __restrict__ Aa,
                                               const u16* __restrict__ Bt,
                                               const float* __restrict__ bias,
                                               const float* __restrict__ resid,
                                               u16* __restrict__ ob0,
                                               u16* __restrict__ ob1,
                                               u16* __restrict__ ob2,
                                               float* __restrict__ of,
                                               int N, int K) {
  __shared__ __align__(16) u16 As[128 * 32];
  __shared__ __align__(16) u16 Bs[128 * 32];
  int n0 = blockIdx.x * 128, m0 = blockIdx.y * 128;
  int tid = threadIdx.x, lane = tid & 63;
  int wave = tid >> 6, wr = wave >> 1, wc = wave & 1;

  f32x4 acc[4][4];
#pragma unroll
  for (int i = 0; i < 4; i++)
#pragma unroll
    for (int j = 0; j < 4; j++) acc[i][j] = (f32x4){0.f, 0.f, 0.f, 0.f};

  int c0 = tid, c1 = tid + 256;
  const u16* Ap0 = Aa + (size_t)(m0 + (c0 >> 2)) * K + (c0 & 3) * 8;
  const u16* Ap1 = Aa + (size_t)(m0 + (c1 >> 2)) * K + (c1 & 3) * 8;
  const u16* Bp0 = Bt + (size_t)(n0 + (c0 >> 2)) * K + (c0 & 3) * 8;
  const u16* Bp1 = Bt + (size_t)(n0 + (c1 >> 2)) * K + (c1 & 3) * 8;
  u16* la0 = As + c0 * 8;
  u16* la1 = As + c1 * 8;
  u16* lb0 = Bs + c0 * 8;
  u16* lb1 = Bs + c1 * 8;

  for (int k0 = 0; k0 < K; k0 += 32) {
    gload_lds16(Ap0 + k0, la0);
    gload_lds16(Ap1 + k0, la1);
    gload_lds16(Bp0 + k0, lb0);
    gload_lds16(Bp1 + k0, lb1);
    __syncthreads();
    bf16x8 af[4], bfr[4];
#pragma unroll
    for (int i = 0; i < 4; i++)
      af[i] = *(const bf16x8*)&As[(wr * 64 + i * 16 + (lane & 15)) * 32 + (lane >> 4) * 8];
#pragma unroll
    for (int j = 0; j < 4; j++)
      bfr[j] = *(const bf16x8*)&Bs[(wc * 64 + j * 16 + (lane & 15)) * 32 + (lane >> 4) * 8];
#pragma unroll
    for (int i = 0; i < 4; i++)
#pragma unroll
      for (int j = 0; j < 4; j++)
        acc[i][j] = __builtin_amdgcn_mfma_f32_16x16x32_bf16(af[i], bfr[j], acc[i][j], 0, 0, 0);
    __syncthreads();
  }

#pragma unroll
  for (int i = 0; i < 4; i++) {
#pragma unroll
    for (int j = 0; j < 4; j++) {
      int mb = m0 + wr * 64 + i * 16 + ((lane >> 4) << 2);
      int n = n0 + wc * 64 + j * 16 + (lane & 15);
      float bv = bias[n];
      float v4[4];
#pragma unroll
      for (int r = 0; r < 4; r++) v4[r] = acc[i][j][r] + bv;
      if (MODE == 0) {
        int b_ = mb >> 11;
        int t = mb & 2047;
        int s = n >> 10;
        int hd = n & 1023;
        int h_ = hd >> 6;
        int d = hd & 63;
        size_t bh = (size_t)b_ * HEADS + h_;
        if (s == 0) {
#pragma unroll
          for (int r = 0; r < 4; r++)
            ob0[(bh * TT + (t + r)) * HD + d] = f2bf(v4[r] * 0.125f);
        } else if (s == 1) {
#pragma unroll
          for (int r = 0; r < 4; r++)
            ob1[(bh * TT + (t + r)) * HD + d] = f2bf(v4[r]);
        } else {
          us4 pk;
#pragma unroll
          for (int r = 0; r < 4; r++) pk[r] = f2bf(v4[r]);
          *(us4*)&ob2[(bh * HD + d) * TT + t] = pk;
        }
      } else if (MODE == 1 || MODE == 3) {
#pragma unroll
        for (int r = 0; r < 4; r++) {
          size_t idx = (size_t)(mb + r) * E + n;
          of[idx] = v4[r] + resid[idx];
        }
      } else {  // MODE 2: exact GELU
#pragma unroll
        for (int r = 0; r < 4; r++)
          ob0[(size_t)(mb + r) * FFD + n] =
              f2bf(0.5f * v4[r] * (1.f + erff(v4[r] * 0.70710678118f)));
      }
    }
  }
}

// ------------- Flash attention -------------
// Q [BH,T,D] bf16 (pre-scaled by 0.125), K [BH,T,D] bf16, Vt [BH,D,T] bf16.
// Block: 256 thr (4 waves), each wave 16 q-rows; KVBLK=64; online softmax.
__global__ void __launch_bounds__(256) attn_kernel(const u16* __restrict__ Qb,
                                                   const u16* __restrict__ Kb,
                                                   const u16* __restrict__ Vt,
                                                   u16* __restrict__ O) {
  int bh = blockIdx.y;
  int q0 = blockIdx.x * 64;
  int b = bh >> 4, h = bh & 15;
  int tid = threadIdx.x, wave = tid >> 6, lane = tid & 63;
  __shared__ __align__(16) u16 Ks[64 * 64];
  __shared__ __align__(16) u16 Vs[64 * 64];
  __shared__ __align__(16) u16 Ps[4 * 16 * 64];

  const u16* Qp = Qb + ((size_t)bh * TT + q0 + wave * 16) * HD;
  bf16x8 qf[2];
#pragma unroll
  for (int c = 0; c < 2; c++)
    qf[c] = *(const bf16x8*)&Qp[(lane & 15) * HD + c * 32 + (lane >> 4) * 8];

  f32x4 oa[4];
#pragma unroll
  for (int dg = 0; dg < 4; dg++) oa[dg] = (f32x4){0.f, 0.f, 0.f, 0.f};
  float m_run[4], l_run[4];
#pragma unroll
  for (int r = 0; r < 4; r++) { m_run[r] = -1e30f; l_run[r] = 0.f; }

  const u16* Kbase = Kb + (size_t)bh * TT * HD;
  const u16* Vbase = Vt + (size_t)bh * HD * TT;
  char* KsB = (char*)Ks;
  char* VsB = (char*)Vs;
  char* PwB = (char*)(Ps + wave * 16 * 64);

  for (int kv0 = 0; kv0 < TT; kv0 += 64) {
    // stage K [kv][d] and V^T [d][kv] tiles, XOR-swizzled 128B rows
    for (int c = tid; c < 512; c += 256) {
      int row = c >> 3;
      int cb = (c & 7) * 16;
      int sb = row * 128 + (cb ^ ((row & 7) << 4));
      *(ushort8*)(KsB + sb) =
          *(const ushort8*)((const char*)(Kbase + (size_t)(kv0 + row) * HD) + cb);
      *(ushort8*)(VsB + sb) =
          *(const ushort8*)((const char*)(Vbase + (size_t)row * TT + kv0) + cb);
    }
    __syncthreads();

    // S = Q K^T  (per wave: 16q x 64kv)
    f32x4 s[4];
#pragma unroll
    for (int g = 0; g < 4; g++) {
      s[g] = (f32x4){0.f, 0.f, 0.f, 0.f};
#pragma unroll
      for (int c = 0; c < 2; c++) {
        int row = g * 16 + (lane & 15);
        int off = row * 128 + ((c * 64 + (lane >> 4) * 16) ^ ((row & 7) << 4));
        bf16x8 kf = *(const bf16x8*)(KsB + off);
        s[g] = __builtin_amdgcn_mfma_f32_16x16x32_bf16(qf[c], kf, s[g], 0, 0, 0);
      }
    }

    // online softmax (rows spread across 16-lane groups)
    float mx[4];
#pragma unroll
    for (int r = 0; r < 4; r++)
      mx[r] = fmaxf(fmaxf(s[0][r], s[1][r]), fmaxf(s[2][r], s[3][r]));
#pragma unroll
    for (int msk = 1; msk < 16; msk <<= 1)
#pragma unroll
      for (int r = 0; r < 4; r++) mx[r] = fmaxf(mx[r], __shfl_xor(mx[r], msk));
    float al[4], psum[4];
#pragma unroll
    for (int r = 0; r < 4; r++) {
      float mn = fmaxf(m_run[r], mx[r]);
      al[r] = __expf(m_run[r] - mn);
      m_run[r] = mn;
      psum[r] = 0.f;
    }
#pragma unroll
    for (int g = 0; g < 4; g++)
#pragma unroll
      for (int r = 0; r < 4; r++) {
        float p = __expf(s[g][r] - m_run[r]);
        s[g][r] = p;
        psum[r] += p;
      }
#pragma unroll
    for (int msk = 1; msk < 16; msk <<= 1)
#pragma unroll
      for (int r = 0; r < 4; r++) psum[r] += __shfl_xor(psum[r], msk);
#pragma unroll
    for (int r = 0; r < 4; r++) l_run[r] = l_run[r] * al[r] + psum[r];
#pragma unroll
    for (int dg = 0; dg < 4; dg++)
#pragma unroll
      for (int r = 0; r < 4; r++) oa[dg][r] *= al[r];

    // P -> per-wave LDS (bf16), C-layout write, A-layout read
#pragma unroll
    for (int g = 0; g < 4; g++)
#pragma unroll
      for (int r = 0; r < 4; r++) {
        int q = (lane >> 4) * 4 + r;
        int cb = (g * 16 + (lane & 15)) * 2;
        *(u16*)(PwB + q * 128 + (cb ^ ((q & 7) << 4))) = f2bf(s[g][r]);
      }
    asm volatile("s_waitcnt lgkmcnt(0)" ::: "memory");

    bf16x8 pf[2];
#pragma unroll
    for (int c = 0; c < 2; c++) {
      int q = lane & 15;
      int off = q * 128 + ((c * 64 + (lane >> 4) * 16) ^ ((q & 7) << 4));
      pf[c] = *(const bf16x8*)(PwB + off);
    }
#pragma unroll
    for (int dg = 0; dg < 4; dg++) {
#pragma unroll
      for (int c = 0; c < 2; c++) {
        int row = dg * 16 + (lane & 15);
        int off = row * 128 + ((c * 64 + (lane >> 4) * 16) ^ ((row & 7) << 4));
        bf16x8 vf = *(const bf16x8*)(VsB + off);
        oa[dg] = __builtin_amdgcn_mfma_f32_16x16x32_bf16(pf[c], vf, oa[dg], 0, 0, 0);
      }
    }
    __syncthreads();
  }

  // epilogue: O[b][q][h*64+d] = oa / l
#pragma unroll
  for (int dg = 0; dg < 4; dg++)
#pragma unroll
    for (int r = 0; r < 4; r++) {
      int q = q0 + wave * 16 + (lane >> 4) * 4 + r;
      int d = dg * 16 + (lane & 15);
      O[((size_t)b * TT + q) * E + h * HD + d] = f2bf(oa[dg][r] / l_run[r]);
    }
}

extern "C" void kernel_launch(void* const* d_in, const int* in_sizes, int n_in,
                              void* d_out, int out_size, void* d_ws, size_t ws_size,
                              hipStream_t stream) {
  (void)in_sizes; (void)n_in; (void)out_size; (void)ws_size;
  const float* x = (const float*)d_in[0];
  const float* qkv_w = (const float*)d_in[1];
  const float* qkv_b = (const float*)d_in[2];
  const float* out_w = (const float*)d_in[3];
  const float* out_b = (const float*)d_in[4];
  const float* ff_w1 = (const float*)d_in[5];
  const float* ff_b1 = (const float*)d_in[6];
  const float* ff_w2 = (const float*)d_in[7];
  const float* ff_b2 = (const float*)d_in[8];
  const float* ln1_g = (const float*)d_in[9];
  const float* ln1_b = (const float*)d_in[10];
  const float* ln2_g = (const float*)d_in[11];
  const float* ln2_b = (const float*)d_in[12];

  char* ws = (char*)d_ws;
  u16* qkvwt = (u16*)(ws + 0);           // 3072x1024 bf16 = 6 MiB
  u16* outwt = (u16*)(ws + 6291456);     // 1024x1024 bf16 = 2 MiB
  u16* ffw1t = (u16*)(ws + 8388608);     // 4096x1024 bf16 = 8 MiB
  u16* ffw2t = (u16*)(ws + 16777216);    // 1024x4096 bf16 = 8 MiB
  u16* ln_out = (u16*)(ws + 25165824);   // 4096x1024 bf16 (ln1 then ln2)
  float* x1 = (float*)(ws + 33554432);   // 4096x1024 fp32 = 16 MiB
  u16* qb = (u16*)(ws + 50331648);       // [32,2048,64] bf16
  u16* kb = (u16*)(ws + 58720256);
  u16* vt = (u16*)(ws + 67108864);       // [32,64,2048] bf16
  u16* attn_o = (u16*)(ws + 75497472);   // 4096x1024 bf16
  u16* hbuf = (u16*)(ws + 50331648);     // 4096x4096 bf16 (aliases q/k/vt/attn_o)

  dim3 tb(32, 8);
  transpose_bf16<<<dim3(3072 / 32, 1024 / 32), tb, 0, stream>>>(qkv_w, qkvwt, 1024, 3072);
  transpose_bf16<<<dim3(1024 / 32, 1024 / 32), tb, 0, stream>>>(out_w, outwt, 1024, 1024);
  transpose_bf16<<<dim3(4096 / 32, 1024 / 32), tb, 0, stream>>>(ff_w1, ffw1t, 1024, 4096);
  transpose_bf16<<<dim3(1024 / 32, 4096 / 32), tb, 0, stream>>>(ff_w2, ffw2t, 4096, 1024);

  ln_kernel<<<MMDIM, 256, 0, stream>>>(x, ln1_g, ln1_b, ln_out);
  gemm_bt<0><<<dim3(3072 / 128, MMDIM / 128), 256, 0, stream>>>(
      ln_out, qkvwt, qkv_b, nullptr, qb, kb, vt, nullptr, 3072, 1024);
  attn_kernel<<<dim3(TT / 64, 32), 256, 0, stream>>>(qb, kb, vt, attn_o);
  gemm_bt<1><<<dim3(1024 / 128, MMDIM / 128), 256, 0, stream>>>(
      attn_o, outwt, out_b, x, nullptr, nullptr, nullptr, x1, 1024, 1024);
  ln_kernel<<<MMDIM, 256, 0, stream>>>(x1, ln2_g, ln2_b, ln_out);
  gemm_bt<2><<<dim3(4096 / 128, MMDIM / 128), 256, 0, stream>>>(
      ln_out, ffw1t, ff_b1, nullptr, hbuf, nullptr, nullptr, nullptr, 4096, 1024);
  gemm_bt<3><<<dim3(1024 / 128, MMDIM / 128), 256, 0, stream>>>(
      hbuf, ffw2t, ff_b2, x1, nullptr, nullptr, nullptr, (float*)d_out, 1024, 4096);
}

// Round 2
// 361.574 us; speedup vs baseline: 1.0334x; 1.0334x over previous
//
#include <hip/hip_runtime.h>

#define E     1024
#define HEADS 16
#define HD    64
#define FFD   4096
#define TT    2048
#define MMDIM 4096   // B*T

typedef __bf16 bf16x8 __attribute__((ext_vector_type(8)));
typedef float f32x4 __attribute__((ext_vector_type(4)));
typedef float f32x16 __attribute__((ext_vector_type(16)));
typedef unsigned short u16;
typedef unsigned u32;
typedef u16 ushort8 __attribute__((ext_vector_type(8)));
typedef u16 us4 __attribute__((ext_vector_type(4)));
typedef u32 u32x4 __attribute__((ext_vector_type(4)));

__device__ __forceinline__ u16 f2bf(float f) {
  unsigned u = __float_as_uint(f);
  u = (u + 0x7fffu + ((u >> 16) & 1u)) >> 16;
  return (u16)u;
}
__device__ __forceinline__ float bf2f(u16 u) {
  return __uint_as_float(((unsigned)u) << 16);
}
__device__ __forceinline__ u32 cvtpk(float a, float b) {
  u32 r;
  asm("v_cvt_pk_bf16_f32 %0, %1, %2" : "=v"(r) : "v"(a), "v"(b));
  return r;
}

__device__ __forceinline__ void gload_lds16(const void* g, void* l) {
  __builtin_amdgcn_global_load_lds((__attribute__((address_space(1))) void*)g,
                                   (__attribute__((address_space(3))) void*)l,
                                   16, 0, 0);
}

// ---------------- LayerNorm: fp32 in -> bf16 out ----------------
__global__ void __launch_bounds__(256) ln_kernel(const float* __restrict__ x,
                                                 const float* __restrict__ g,
                                                 const float* __restrict__ b,
                                                 u16* __restrict__ out) {
  int row = blockIdx.x;
  int t = threadIdx.x;
  const float4 v = reinterpret_cast<const float4*>(x + (size_t)row * E)[t];
  float s = v.x + v.y + v.z + v.w;
  float s2 = v.x * v.x + v.y * v.y + v.z * v.z + v.w * v.w;
#pragma unroll
  for (int m = 1; m < 64; m <<= 1) {
    s += __shfl_xor(s, m);
    s2 += __shfl_xor(s2, m);
  }
  __shared__ float red[8];
  int wave = t >> 6, lane = t & 63;
  if (lane == 0) { red[wave] = s; red[wave + 4] = s2; }
  __syncthreads();
  s = red[0] + red[1] + red[2] + red[3];
  s2 = red[4] + red[5] + red[6] + red[7];
  float mean = s * (1.f / E);
  float var = s2 * (1.f / E) - mean * mean;
  float inv = rsqrtf(var + 1e-5f);
  const float4 gv = reinterpret_cast<const float4*>(g)[t];
  const float4 bv = reinterpret_cast<const float4*>(b)[t];
  us4 pk;
  pk.x = f2bf((v.x - mean) * inv * gv.x + bv.x);
  pk.y = f2bf((v.y - mean) * inv * gv.y + bv.y);
  pk.z = f2bf((v.z - mean) * inv * gv.z + bv.z);
  pk.w = f2bf((v.w - mean) * inv * gv.w + bv.w);
  *(us4*)(out + (size_t)row * E + t * 4) = pk;
}

// ------------- Transpose+convert: W[K,N] fp32 -> Wt[N,K] bf16 -------------
__global__ void __launch_bounds__(256) transpose_bf16(const float* __restrict__ in,
                                                      u16* __restrict__ out,
                                                      int K, int N) {
  __shared__ float tile[32][33];
  int k0 = blockIdx.y * 32, n0 = blockIdx.x * 32;
  int tx = threadIdx.x, ty = threadIdx.y;  // block (32,8)
#pragma unroll
  for (int i = ty; i < 32; i += 8)
    tile[i][tx] = in[(size_t)(k0 + i) * N + n0 + tx];
  __syncthreads();
#pragma unroll
  for (int i = ty; i < 32; i += 8)
    out[(size_t)(n0 + i) * K + k0 + tx] = f2bf(tile[tx][i]);
}

// ------------- GEMM C[M,N] = A[M,K](bf16) @ Bt[N,K](bf16)^T -------------
// m97 structure: 128x128 tile, BK=32, 4 waves (2x2), 4x4 16x16 frags/wave.
// MODE 0: +qkv_b, scatter Q(*0.125)/K -> [BH,T,D], V -> [BH,D,T]
// MODE 1: +out_b +resid -> fp32 of
// MODE 2: +ff_b1, exact GELU -> bf16 ob0
// MODE 4: split-K partial (no bias) -> bf16 ob0 at z*pstride
template <int MODE>
__global__ void __launch_bounds__(256) gemm_bt(const u16* __restrict__ Aa,
                                               const u16* __restrict__ Bt,
                                               const float* __restrict__ bias,
                                               const float* __restrict__ resid,
                                               u16* __restrict__ ob0,
                                               u16* __restrict__ ob1,
                                               u16* __restrict__ ob2,
                                               float* __restrict__ of,
                                               int N, int K, int lda, int ldb,
                                               int pstride) {
  __shared__ __align__(16) u16 As[128 * 32];
  __shared__ __align__(16) u16 Bs[128 * 32];
  int n0 = blockIdx.x * 128, m0 = blockIdx.y * 128;
  int tid = threadIdx.x, lane = tid & 63;
  int wave = tid >> 6, wr = wave >> 1, wc = wave & 1;
  size_t koff = (size_t)blockIdx.z * K;

  f32x4 acc[4][4];
#pragma unroll
  for (int i = 0; i < 4; i++)
#pragma unroll
    for (int j = 0; j < 4; j++) acc[i][j] = (f32x4){0.f, 0.f, 0.f, 0.f};

  int c0 = tid, c1 = tid + 256;
  const u16* Ap0 = Aa + (size_t)(m0 + (c0 >> 2)) * lda + koff + (c0 & 3) * 8;
  const u16* Ap1 = Aa + (size_t)(m0 + (c1 >> 2)) * lda + koff + (c1 & 3) * 8;
  const u16* Bp0 = Bt + (size_t)(n0 + (c0 >> 2)) * ldb + koff + (c0 & 3) * 8;
  const u16* Bp1 = Bt + (size_t)(n0 + (c1 >> 2)) * ldb + koff + (c1 & 3) * 8;
  u16* la0 = As + c0 * 8;
  u16* la1 = As + c1 * 8;
  u16* lb0 = Bs + c0 * 8;
  u16* lb1 = Bs + c1 * 8;

  for (int k0 = 0; k0 < K; k0 += 32) {
    gload_lds16(Ap0 + k0, la0);
    gload_lds16(Ap1 + k0, la1);
    gload_lds16(Bp0 + k0, lb0);
    gload_lds16(Bp1 + k0, lb1);
    __syncthreads();
    bf16x8 af[4], bfr[4];
#pragma unroll
    for (int i = 0; i < 4; i++)
      af[i] = *(const bf16x8*)&As[(wr * 64 + i * 16 + (lane & 15)) * 32 + (lane >> 4) * 8];
#pragma unroll
    for (int j = 0; j < 4; j++)
      bfr[j] = *(const bf16x8*)&Bs[(wc * 64 + j * 16 + (lane & 15)) * 32 + (lane >> 4) * 8];
#pragma unroll
    for (int i = 0; i < 4; i++)
#pragma unroll
      for (int j = 0; j < 4; j++)
        acc[i][j] = __builtin_amdgcn_mfma_f32_16x16x32_bf16(af[i], bfr[j], acc[i][j], 0, 0, 0);
    __syncthreads();
  }

#pragma unroll
  for (int i = 0; i < 4; i++) {
#pragma unroll
    for (int j = 0; j < 4; j++) {
      int mb = m0 + wr * 64 + i * 16 + ((lane >> 4) << 2);
      int n = n0 + wc * 64 + j * 16 + (lane & 15);
      float bv = (MODE == 4) ? 0.f : bias[n];
      float v4[4];
#pragma unroll
      for (int r = 0; r < 4; r++) v4[r] = acc[i][j][r] + bv;
      if (MODE == 0) {
        int b_ = mb >> 11;
        int t = mb & 2047;
        int s = n >> 10;
        int hd = n & 1023;
        int h_ = hd >> 6;
        int d = hd & 63;
        size_t bh = (size_t)b_ * HEADS + h_;
        if (s == 0) {
#pragma unroll
          for (int r = 0; r < 4; r++)
            ob0[(bh * TT + (t + r)) * HD + d] = f2bf(v4[r] * 0.125f);
        } else if (s == 1) {
#pragma unroll
          for (int r = 0; r < 4; r++)
            ob1[(bh * TT + (t + r)) * HD + d] = f2bf(v4[r]);
        } else {
          us4 pk;
#pragma unroll
          for (int r = 0; r < 4; r++) pk[r] = f2bf(v4[r]);
          *(us4*)&ob2[(bh * HD + d) * TT + t] = pk;
        }
      } else if (MODE == 1) {
#pragma unroll
        for (int r = 0; r < 4; r++) {
          size_t idx = (size_t)(mb + r) * E + n;
          of[idx] = v4[r] + resid[idx];
        }
      } else if (MODE == 2) {  // exact GELU
#pragma unroll
        for (int r = 0; r < 4; r++)
          ob0[(size_t)(mb + r) * FFD + n] =
              f2bf(0.5f * v4[r] * (1.f + erff(v4[r] * 0.70710678118f)));
      } else {  // MODE 4: bf16 partial
        size_t zoff = (size_t)blockIdx.z * pstride;
#pragma unroll
        for (int r = 0; r < 4; r++)
          ob0[zoff + (size_t)(mb + r) * N + n] = f2bf(v4[r]);
      }
    }
  }
}

// ------------- FF2 split-K reduce: out = resid + bias + p0 + p1 -------------
__global__ void __launch_bounds__(256) ff2_reduce(const u16* __restrict__ p0,
                                                  const u16* __restrict__ p1,
                                                  const float* __restrict__ bias,
                                                  const float* __restrict__ resid,
                                                  float* __restrict__ out) {
  size_t i = ((size_t)blockIdx.x * 256 + threadIdx.x) * 4;
  int n = (int)(i & (E - 1));
  us4 a = *(const us4*)(p0 + i);
  us4 c = *(const us4*)(p1 + i);
  float4 r = *(const float4*)(resid + i);
  const float4 bs = *(const float4*)(bias + n);
  float4 o;
  o.x = r.x + bs.x + bf2f(a.x) + bf2f(c.x);
  o.y = r.y + bs.y + bf2f(a.y) + bf2f(c.y);
  o.z = r.z + bs.z + bf2f(a.z) + bf2f(c.z);
  o.w = r.w + bs.w + bf2f(a.w) + bf2f(c.w);
  *(float4*)(out + i) = o;
}

// ------------- Flash attention, swapped-operand 32x32 structure -------------
// Q [BH,T,D] bf16 (pre-scaled by 0.125), K [BH,T,D] bf16, Vt [BH,D,T] bf16.
// 1 wave per 32 q-rows. S^T = mfma(K, Q) -> q is lane-local (col = lane&31).
// No LDS, no barriers; K/V direct from global (L2-resident, 512KB per bh).
// Grid: bid = qb*32 + bh  =>  bid%8 = bh%8: all q-blocks of a bh on one XCD.
__global__ void __launch_bounds__(64) attn_kernel(const u16* __restrict__ Qb,
                                                  const u16* __restrict__ Kb,
                                                  const u16* __restrict__ Vt,
                                                  u16* __restrict__ O) {
  int bid = blockIdx.x;
  int bh = bid & 31;
  int q0 = (bid >> 5) << 5;
  int b = bh >> 4, h = bh & 15;
  int lane = threadIdx.x;
  int lq = lane & 31, hi = lane >> 5;

  // Q as B-operand: col q = lane&31, k(d) = c*16 + hi*8 + j
  const u16* Qp = Qb + ((size_t)bh * TT + q0 + lq) * HD + hi * 8;
  bf16x8 qf[4];
#pragma unroll
  for (int c = 0; c < 4; c++) qf[c] = *(const bf16x8*)(Qp + c * 16);

  const u16* Kbase = Kb + ((size_t)bh * TT + lq) * HD + hi * 8;
  const u16* Vbase = Vt + ((size_t)bh * HD + lq) * TT + hi * 8;

  f32x16 o0, o1;
#pragma unroll
  for (int r = 0; r < 16; r++) { o0[r] = 0.f; o1[r] = 0.f; }
  float m_run = -1e30f, l_run = 0.f;

  for (int kv0 = 0; kv0 < TT; kv0 += 32) {
    // K as A-operand: row kv = lane&31, k(d) = c*16 + hi*8 + j
    const u16* Kp = Kbase + (size_t)kv0 * HD;
    bf16x8 kf[4];
#pragma unroll
    for (int c = 0; c < 4; c++) kf[c] = *(const bf16x8*)(Kp + c * 16);

    f32x16 s;
#pragma unroll
    for (int r = 0; r < 16; r++) s[r] = 0.f;
#pragma unroll
    for (int c = 0; c < 4; c++)
      s = __builtin_amdgcn_mfma_f32_32x32x16_bf16(kf[c], qf[c], s, 0, 0, 0);
    // lane holds S^T rows kv = (r&3)+8*(r>>2)+4*hi, col q = lq

    float mx = s[0];
#pragma unroll
    for (int r = 1; r < 16; r++) mx = fmaxf(mx, s[r]);
    mx = fmaxf(mx, __shfl_xor(mx, 32));

    if (__any(mx > m_run + 8.f)) {  // T13 defer-max
      float mn = fmaxf(m_run, mx);
      float al = __expf(m_run - mn);
#pragma unroll
      for (int r = 0; r < 16; r++) { o0[r] *= al; o1[r] *= al; }
      l_run *= al;
      m_run = mn;
    }

    float p[16], ps = 0.f;
#pragma unroll
    for (int r = 0; r < 16; r++) {
      p[r] = __expf(s[r] - m_run);
      ps += p[r];
    }
    l_run += ps + __shfl_xor(ps, 32);

    // P^T B-frags via cvt_pk + lane^32 exchange (T12, shfl form)
    u32 w[8];
#pragma unroll
    for (int c = 0; c < 2; c++) {
      u32 qA = cvtpk(p[c * 8 + 0], p[c * 8 + 1]);
      u32 qB = cvtpk(p[c * 8 + 2], p[c * 8 + 3]);
      u32 qC = cvtpk(p[c * 8 + 4], p[c * 8 + 5]);
      u32 qD = cvtpk(p[c * 8 + 6], p[c * 8 + 7]);
      u32 As_ = __shfl_xor(qA, 32), Bs_ = __shfl_xor(qB, 32);
      u32 Cs_ = __shfl_xor(qC, 32), Ds_ = __shfl_xor(qD, 32);
      w[c * 4 + 0] = hi ? Cs_ : qA;
      w[c * 4 + 1] = hi ? Ds_ : qB;
      w[c * 4 + 2] = hi ? qC : As_;
      w[c * 4 + 3] = hi ? qD : Bs_;
    }
    u32x4 t0 = {w[0], w[1], w[2], w[3]};
    u32x4 t1 = {w[4], w[5], w[6], w[7]};
    bf16x8 pf0 = __builtin_bit_cast(bf16x8, t0);
    bf16x8 pf1 = __builtin_bit_cast(bf16x8, t1);

    // O^T += V^T P^T : V^T as A-operand (row d = lane&31, k(kv) = c*16+hi*8+j)
    const u16* Vp = Vbase + kv0;
    bf16x8 v00 = *(const bf16x8*)(Vp);
    bf16x8 v01 = *(const bf16x8*)(Vp + 16);
    bf16x8 v10 = *(const bf16x8*)(Vp + (size_t)32 * TT);
    bf16x8 v11 = *(const bf16x8*)(Vp + (size_t)32 * TT + 16);
    o0 = __builtin_amdgcn_mfma_f32_32x32x16_bf16(v00, pf0, o0, 0, 0, 0);
    o0 = __builtin_amdgcn_mfma_f32_32x32x16_bf16(v01, pf1, o0, 0, 0, 0);
    o1 = __builtin_amdgcn_mfma_f32_32x32x16_bf16(v10, pf0, o1, 0, 0, 0);
    o1 = __builtin_amdgcn_mfma_f32_32x32x16_bf16(v11, pf1, o1, 0, 0, 0);
  }

  float rl = 1.f / l_run;
  const size_t orow = ((size_t)b * TT + q0 + lq) * E + h * HD;
#pragma unroll
  for (int r = 0; r < 16; r++) {
    int d = (r & 3) + ((r >> 2) << 3) + (hi << 2);
    O[orow + d] = f2bf(o0[r] * rl);
    O[orow + 32 + d] = f2bf(o1[r] * rl);
  }
}

extern "C" void kernel_launch(void* const* d_in, const int* in_sizes, int n_in,
                              void* d_out, int out_size, void* d_ws, size_t ws_size,
                              hipStream_t stream) {
  (void)in_sizes; (void)n_in; (void)out_size; (void)ws_size;
  const float* x = (const float*)d_in[0];
  const float* qkv_w = (const float*)d_in[1];
  const float* qkv_b = (const float*)d_in[2];
  const float* out_w = (const float*)d_in[3];
  const float* out_b = (const float*)d_in[4];
  const float* ff_w1 = (const float*)d_in[5];
  const float* ff_b1 = (const float*)d_in[6];
  const float* ff_w2 = (const float*)d_in[7];
  const float* ff_b2 = (const float*)d_in[8];
  const float* ln1_g = (const float*)d_in[9];
  const float* ln1_b = (const float*)d_in[10];
  const float* ln2_g = (const float*)d_in[11];
  const float* ln2_b = (const float*)d_in[12];

  char* ws = (char*)d_ws;
  u16* qkvwt = (u16*)(ws + 0);           // 3072x1024 bf16 = 6 MiB   (dead after QKV gemm)
  u16* outwt = (u16*)(ws + 6291456);     // 1024x1024 bf16 = 2 MiB   (dead after proj)
  u16* ffw1t = (u16*)(ws + 8388608);     // 4096x1024 bf16 = 8 MiB   (dead after FF1)
  u16* ffw2t = (u16*)(ws + 16777216);    // 1024x4096 bf16 = 8 MiB
  u16* ln_out = (u16*)(ws + 25165824);   // 4096x1024 bf16 (ln1 then ln2)
  float* x1 = (float*)(ws + 33554432);   // 4096x1024 fp32 = 16 MiB
  u16* qb = (u16*)(ws + 50331648);       // [32,2048,64] bf16
  u16* kb = (u16*)(ws + 58720256);
  u16* vt = (u16*)(ws + 67108864);       // [32,64,2048] bf16
  u16* attn_o = (u16*)(ws + 75497472);   // 4096x1024 bf16
  u16* hbuf = (u16*)(ws + 50331648);     // 4096x4096 bf16 (aliases q/k/vt/attn_o)
  u16* pbuf = (u16*)(ws + 0);            // 2x 4096x1024 bf16 partials (aliases dead weights)

  dim3 tb(32, 8);
  transpose_bf16<<<dim3(3072 / 32, 1024 / 32), tb, 0, stream>>>(qkv_w, qkvwt, 1024, 3072);
  transpose_bf16<<<dim3(1024 / 32, 1024 / 32), tb, 0, stream>>>(out_w, outwt, 1024, 1024);
  transpose_bf16<<<dim3(4096 / 32, 1024 / 32), tb, 0, stream>>>(ff_w1, ffw1t, 1024, 4096);
  transpose_bf16<<<dim3(1024 / 32, 4096 / 32), tb, 0, stream>>>(ff_w2, ffw2t, 4096, 1024);

  ln_kernel<<<MMDIM, 256, 0, stream>>>(x, ln1_g, ln1_b, ln_out);
  gemm_bt<0><<<dim3(3072 / 128, MMDIM / 128), 256, 0, stream>>>(
      ln_out, qkvwt, qkv_b, nullptr, qb, kb, vt, nullptr, 3072, 1024, 1024, 1024, 0);
  attn_kernel<<<dim3((TT / 32) * 32), 64, 0, stream>>>(qb, kb, vt, attn_o);
  gemm_bt<1><<<dim3(1024 / 128, MMDIM / 128), 256, 0, stream>>>(
      attn_o, outwt, out_b, x, nullptr, nullptr, nullptr, x1, 1024, 1024, 1024, 1024, 0);
  ln_kernel<<<MMDIM, 256, 0, stream>>>(x1, ln2_g, ln2_b, ln_out);
  gemm_bt<2><<<dim3(4096 / 128, MMDIM / 128), 256, 0, stream>>>(
      ln_out, ffw1t, ff_b1, nullptr, hbuf, nullptr, nullptr, nullptr, 4096, 1024, 1024, 1024, 0);
  gemm_bt<4><<<dim3(1024 / 128, MMDIM / 128, 2), 256, 0, stream>>>(
      hbuf, ffw2t, nullptr, nullptr, pbuf, nullptr, nullptr, nullptr, 1024, 2048, 4096, 4096,
      MMDIM * E);
  ff2_reduce<<<MMDIM * E / 1024, 256, 0, stream>>>(pbuf, pbuf + (size_t)MMDIM * E, ff_b2, x1,
                                                   (float*)d_out);
}